// Round 2
// baseline (357.718 us; speedup 1.0000x reference)
//
#include <hip/hip_runtime.h>
#include <hip/hip_bf16.h>

// Problem: B=8, C=256, H=W=96, c8=32, pool sizes {1,3,5,7,14} -> 280 positions.
// Restructured: out[b,o] = sum_k aff[b,o,k] * conv3x3(x_1[b], con[k])
//               psp(wq@x+bq) = wq@psp(x)+bq  (pool rows sum to 1)
// yconv as implicit-GEMM bf16 MFMA; mix as MFMA GEMM over K=32 with kc summed
// in the accumulator (Yp layout [kc][b][px][k], aff stored bf16 [b][o][k]).

#define B 8
#define C 256
#define C8 32
#define H 96
#define W 96
#define HW 9216
#define NPOS 280
#define NWBIN 30
#define PLS 100   // plane LDS stride (floats)
#define RPS 108   // rowp stride (floats), aliases plane after phase 1

typedef __attribute__((ext_vector_type(8))) short short8;
typedef __attribute__((ext_vector_type(4))) float float4v;
typedef __attribute__((ext_vector_type(4))) unsigned short ushort4v;

static __device__ __forceinline__ unsigned short f2bf(float f) {
    unsigned u = __float_as_uint(f);
    unsigned r = (u + 0x7FFF + ((u >> 16) & 1)) >> 16;   // RNE
    return (unsigned short)r;
}

// Accumulate one half-row (48 elems starting at compile-time W0) into the 30
// w-bins. All bin edges are compile-time constants -> straight-line v_add_f32.
template<int W0>
static __device__ __forceinline__ void accum_half_row(const float* __restrict__ pl,
                                                      float acc[NWBIN]) {
    const int SC[5]   = {1, 3, 5, 7, 14};
    const int WOFF[5] = {0, 1, 4, 9, 16};
    #pragma unroll
    for (int k = 0; k < NWBIN; ++k) acc[k] = 0.f;
    #pragma unroll
    for (int c = 0; c < 12; ++c) {
        float4 v = *(const float4*)&pl[W0 + 4 * c];
        float vv[4] = {v.x, v.y, v.z, v.w};
        #pragma unroll
        for (int q = 0; q < 4; ++q) {
            const int w = W0 + 4 * c + q;
            #pragma unroll
            for (int si = 0; si < 5; ++si) {
                #pragma unroll
                for (int j = 0; j < SC[si]; ++j) {
                    const int st = (j * 96) / SC[si];
                    const int en = (96 * (j + 1) + SC[si] - 1) / SC[si];
                    if (w >= st && w < en) acc[WOFF[si] + j] += vv[q];
                }
            }
        }
    }
}

// ---------------- pooling: [B,C,96,96] -> [B,C,280] for both x_1 and x ----
// LDS = plane only (38.4 KB) -> 4 blocks/CU; rowp aliases plane (regs carry
// the w-bin partials across the extra barrier).
__global__ __launch_bounds__(256) void pool_kernel(const float* __restrict__ x1,
                                                   const float* __restrict__ x,
                                                   float* __restrict__ px1,
                                                   float* __restrict__ px) {
    __shared__ __align__(16) float plane[96 * PLS];   // 38400 B
    float* rowp = plane;                              // alias after phase 1
    const int bi = blockIdx.x;           // 0..4095
    const int which = bi >> 11;          // 0: x_1, 1: x
    const int bc = bi & 2047;
    const float* __restrict__ src = (which ? x : x1) + (size_t)bc * HW;
    float* __restrict__ dst = (which ? px : px1) + (size_t)bc * NPOS;
    const int tid = threadIdx.x;

    const int SC[5]   = {1, 3, 5, 7, 14};
    const int WOFF[5] = {0, 1, 4, 9, 16};
    const int POFF[5] = {0, 1, 10, 35, 84};

    // stage plane: coalesced float4 global -> b128 LDS, stride-100 rows
    const float4* __restrict__ src4 = (const float4*)src;
    #pragma unroll
    for (int it = 0; it < 9; ++it) {
        int idx = tid + it * 256;        // 0..2303
        float4 v = src4[idx];
        int h = idx / 24;
        int w4 = idx - h * 24;
        *(float4*)&plane[h * PLS + w4 * 4] = v;
    }
    __syncthreads();

    // phase 1: w-bin accumulation into registers, one thread per half-row
    float acc[NWBIN];
    if (tid < 96) {                              // rows, w in [0,48)
        accum_half_row<0>(&plane[tid * PLS], acc);
    } else if (tid >= 128 && tid < 224) {        // rows, w in [48,96)
        accum_half_row<48>(&plane[(tid - 128) * PLS], acc);
    }
    __syncthreads();          // ALL plane reads complete; safe to alias

    if (tid >= 128 && tid < 224) {
        const int h1 = tid - 128;
        #pragma unroll
        for (int si = 0; si < 5; ++si) {
            #pragma unroll
            for (int j = 0; j < SC[si]; ++j)
                rowp[(WOFF[si] + j) * RPS + h1] = acc[WOFF[si] + j];
        }
    }
    __syncthreads();
    // combine halves + scale by 1/(w-bin width)
    if (tid < 96) {
        #pragma unroll
        for (int si = 0; si < 5; ++si) {
            #pragma unroll
            for (int j = 0; j < SC[si]; ++j) {
                const int st = (j * 96) / SC[si];
                const int en = (96 * (j + 1) + SC[si] - 1) / SC[si];
                const float inv = 1.0f / (float)(en - st);
                const int bin = WOFF[si] + j;
                rowp[bin * RPS + tid] = (acc[bin] + rowp[bin * RPS + tid]) * inv;
            }
        }
    }
    __syncthreads();

    // phase C: in-place prefix sum over h per w-bin (30 threads, b128)
    if (tid < NWBIN) {
        float run = 0.f;
        #pragma unroll
        for (int c = 0; c < 24; ++c) {
            float4 v = *(const float4*)&rowp[tid * RPS + 4 * c];
            v.x += run; v.y += v.x; v.z += v.y; v.w += v.z;
            run = v.w;
            *(float4*)&rowp[tid * RPS + 4 * c] = v;
        }
    }
    __syncthreads();

    // phase D: 280 outputs, each = prefix difference * 1/(h-bin width)
    for (int p = tid; p < NPOS; p += 256) {
        int si;
        if (p < 1) si = 0; else if (p < 10) si = 1; else if (p < 35) si = 2;
        else if (p < 84) si = 3; else si = 4;
        int s = SC[si];
        int loc = p - POFF[si];
        int i = loc / s;
        int j = loc - i * s;
        int st = (i * 96) / s;
        int en = (96 * (i + 1) + s - 1) / s;
        int binrow = WOFF[si] + j;
        float hi = rowp[binrow * RPS + (en - 1)];
        float lo = (st > 0) ? rowp[binrow * RPS + (st - 1)] : 0.f;
        dst[p] = (hi - lo) * (1.0f / (float)(en - st));
    }
}

// ---------------- proj: PQ = wq@px1+bq [B,256,280]; PK = wk@px+bk [B,32,280]
__global__ __launch_bounds__(320) void proj_kernel(const float* __restrict__ px1,
                                                   const float* __restrict__ px,
                                                   const float* __restrict__ wq,
                                                   const float* __restrict__ bq,
                                                   const float* __restrict__ wk,
                                                   const float* __restrict__ bk,
                                                   float* __restrict__ PQ,
                                                   float* __restrict__ PK) {
    const int bi = blockIdx.x;   // B * 72
    const int b = bi / 72;
    const int r = bi % 72;
    const int tid = threadIdx.x;
    const float* src;
    const float* wm;
    const float* bias;
    float* dst;
    int o0;
    if (r < 64) {
        o0 = r * 4;
        src = px1 + (size_t)b * C * NPOS;
        wm = wq; bias = bq;
        dst = PQ + ((size_t)b * C + o0) * NPOS;
    } else {
        o0 = (r - 64) * 4;
        src = px + (size_t)b * C * NPOS;
        wm = wk; bias = bk;
        dst = PK + ((size_t)b * C8 + o0) * NPOS;
    }
    if (tid >= NPOS) return;
    float a0 = 0.f, a1 = 0.f, a2 = 0.f, a3 = 0.f;
    for (int c = 0; c < C; ++c) {
        float xv = src[c * NPOS + tid];
        a0 += wm[(o0 + 0) * C + c] * xv;
        a1 += wm[(o0 + 1) * C + c] * xv;
        a2 += wm[(o0 + 2) * C + c] * xv;
        a3 += wm[(o0 + 3) * C + c] * xv;
    }
    dst[0 * NPOS + tid] = a0 + bias[o0 + 0];
    dst[1 * NPOS + tid] = a1 + bias[o0 + 1];
    dst[2 * NPOS + tid] = a2 + bias[o0 + 2];
    dst[3 * NPOS + tid] = a3 + bias[o0 + 3];
}

// ---------------- aff[b,o,k] = sigmoid(PQ[b,o,:] . PK[b,k,:]) -> bf16 ------
__global__ __launch_bounds__(256) void aff_kernel(const float* __restrict__ PQ,
                                                  const float* __restrict__ PK,
                                                  unsigned short* __restrict__ affb) {
    __shared__ float pk[NPOS];
    const int b = blockIdx.x >> 5;
    const int k = blockIdx.x & 31;
    const int tid = threadIdx.x;
    const float* __restrict__ pkr = PK + ((size_t)b * C8 + k) * NPOS;
    if (tid < 256) pk[tid] = pkr[tid];
    if (tid < NPOS - 256) pk[tid + 256] = pkr[tid + 256];
    __syncthreads();
    const float4* __restrict__ q4 = (const float4*)(PQ + ((size_t)b * C + tid) * NPOS);
    const float4* __restrict__ p4 = (const float4*)pk;
    float acc = 0.f;
    #pragma unroll 10
    for (int i = 0; i < NPOS / 4; ++i) {
        float4 a = q4[i];
        float4 c = p4[i];
        acc += a.x * c.x + a.y * c.y + a.z * c.z + a.w * c.w;
    }
    float s = 1.0f / (1.0f + __expf(-acc));
    affb[((size_t)b * C + tid) * C8 + k] = f2bf(s);
}

// ---------------- prep: con[k,c,3,3] -> Aswz in MFMA A-fragment order ------
__global__ __launch_bounds__(256) void aswz_kernel(const float* __restrict__ con,
                                                   unsigned short* __restrict__ aswz) {
    int idx = blockIdx.x * 256 + threadIdx.x;   // 72*2*64*8 = 73728
    if (idx >= 73728) return;
    int j = idx & 7;
    int lane = (idx >> 3) & 63;
    int mt = (idx >> 9) & 1;
    int s = idx >> 10;          // 0..71
    int pos = s >> 3;
    int cg = s & 7;
    int m = lane & 15, quad = lane >> 4;
    int ko = mt * 16 + m;
    int c = cg * 32 + quad * 8 + j;
    int dy = pos / 3, dx = pos - dy * 3;
    float v = con[((ko * C + c) * 3 + dy) * 3 + dx];
    aswz[idx] = f2bf(v);
}

// ---------------- transpose x1[b,c,pix] f32 -> xbf[b,pix,c] bf16 -----------
__global__ __launch_bounds__(256) void x2bf_kernel(const float* __restrict__ x1,
                                                   unsigned short* __restrict__ xbf) {
    __shared__ unsigned short tl[64 * 65];
    const int bi = blockIdx.x;
    const int b = bi / 576;
    const int rem = bi % 576;
    const int pt = rem >> 2;
    const int ct = rem & 3;
    const int p0 = pt * 64, c0 = ct * 64;
    const int wid = threadIdx.x >> 6;
    const int lane = threadIdx.x & 63;

    #pragma unroll
    for (int it = 0; it < 16; ++it) {
        int r = it * 4 + wid;   // channel within tile
        tl[r * 65 + lane] = f2bf(x1[((size_t)(b * C + c0 + r)) * HW + p0 + lane]);
    }
    __syncthreads();
    #pragma unroll
    for (int it = 0; it < 16; ++it) {
        int pr = it * 4 + wid;  // pixel within tile
        xbf[((size_t)b * HW + p0 + pr) * 256 + c0 + lane] = tl[lane * 65 + pr];
    }
}

// ---------------- Y = W @ im2col(x1) via MFMA, K split over 4 blocks -------
// Output layout: Yp[kc][b][px][k] bf16 (k contiguous) for MFMA-ready mix.
__global__ __launch_bounds__(256) void yconv_mfma(const unsigned short* __restrict__ xbf,
                                                  const unsigned short* __restrict__ aswz,
                                                  unsigned short* __restrict__ Yp) {
    __shared__ unsigned short xsl[10 * 50 * 40];   // [row][col][ch pad 40] = 40000 B
    const int bi = blockIdx.x;
    const int kc = bi & 3;
    const int rest = bi >> 2;          // 0..191
    const int tilex = rest & 1;
    const int tiley = (rest >> 1) % 12;
    const int b = rest / 24;
    const int tid = threadIdx.x;
    const int wid = tid >> 6;
    const int lane = tid & 63;
    const int n = lane & 15, quad = lane >> 4;

    float4v acc[2][6];
    #pragma unroll
    for (int mt = 0; mt < 2; ++mt)
        #pragma unroll
        for (int t = 0; t < 6; ++t)
            acc[mt][t] = (float4v){0.f, 0.f, 0.f, 0.f};

    int baseb[6];
    #pragma unroll
    for (int t = 0; t < 6; ++t) {
        int tt = wid * 6 + t;
        int rt = tt / 3;
        int xb = (tt % 3) * 16;
        baseb[t] = (rt * 50 + xb + n) * 40 + quad * 8;
    }

    for (int ci = 0; ci < 2; ++ci) {
        const int cg = kc * 2 + ci;
        __syncthreads();
        // stage X slab: 10 rows x 50 cols x 32 ch bf16, pure uint4 copies
        for (int task = tid; task < 2000; task += 256) {
            int pix = task >> 2;       // 0..499
            int cq = task & 3;
            int r = pix / 50;
            int col = pix - r * 50;
            int gy = tiley * 8 + r - 1;
            int gx = tilex * 48 + col - 1;
            uint4 v = make_uint4(0u, 0u, 0u, 0u);
            if ((unsigned)gy < 96u && (unsigned)gx < 96u)
                v = *(const uint4*)&xbf[((size_t)b * HW + gy * 96 + gx) * 256 + cg * 32 + cq * 8];
            *(uint4*)&xsl[(r * 50 + col) * 40 + cq * 8] = v;
        }
        // A-fragments straight from global (L2-hot, 18 x 16B per lane)
        short8 af[9][2];
        #pragma unroll
        for (int pos = 0; pos < 9; ++pos)
            #pragma unroll
            for (int mt = 0; mt < 2; ++mt)
                af[pos][mt] = *(const short8*)&aswz[((((pos * 8 + cg) * 2) + mt) * 64 + lane) * 8];
        __syncthreads();

        #pragma unroll
        for (int pos = 0; pos < 9; ++pos) {
            const int dy = pos / 3, dx = pos - (pos / 3) * 3;
            const int d = (dy * 50 + dx) * 40;
            #pragma unroll
            for (int t = 0; t < 6; ++t) {
                short8 bf = *(const short8*)&xsl[baseb[t] + d];
                acc[0][t] = __builtin_amdgcn_mfma_f32_16x16x32_bf16(af[pos][0], bf, acc[0][t], 0, 0, 0);
                acc[1][t] = __builtin_amdgcn_mfma_f32_16x16x32_bf16(af[pos][1], bf, acc[1][t], 0, 0, 0);
            }
        }
    }

    // store partial: D col=lane&15 -> pixel n, row=quad*4+reg -> k_out.
    // Layout [kc][b][px][k]: 4 consecutive regs = 4 consecutive k -> 8B store.
    #pragma unroll
    for (int mt = 0; mt < 2; ++mt) {
        #pragma unroll
        for (int t = 0; t < 6; ++t) {
            int tt = wid * 6 + t;
            int rt = tt / 3;
            int xb = (tt % 3) * 16;
            int gy = tiley * 8 + rt;
            int gx = tilex * 48 + xb + n;
            ushort4v v;
            #pragma unroll
            for (int reg = 0; reg < 4; ++reg) v[reg] = f2bf(acc[mt][t][reg]);
            *(ushort4v*)&Yp[((((size_t)kc * B + b) * HW + gy * 96 + gx)) * C8 + mt * 16 + quad * 4] = v;
        }
    }
}

// ---------------- mix: out[b,o,px] = sum_k aff[b,o,k] * sum_kc Yp ----------
// Pure-register MFMA GEMM: A = aff bf16 [o][k], B = Yp [px][k], K=32 = one
// MFMA per (tile,kc); kc summed in the accumulator. No LDS.
// grid = 8 b * 16 mtiles * 9 px-groups(1024) = 1152 blocks, 4 waves.
__global__ __launch_bounds__(256) void mix_kernel(const unsigned short* __restrict__ Yp,
                                                  const unsigned short* __restrict__ affb,
                                                  float* __restrict__ out) {
    const int bi = blockIdx.x;   // 1152
    const int b = bi / 144;
    const int rem = bi % 144;
    const int mt = rem / 9;      // 0..15 -> o0 = mt*16
    const int pg = rem % 9;      // 1024-px group
    const int wid = threadIdx.x >> 6;
    const int lane = threadIdx.x & 63;
    const int n = lane & 15, quad = lane >> 4;
    const int o0 = mt * 16;
    const int px0 = pg * 1024 + wid * 256;

    // A-frag: A[m=lane&15][k=quad*8+j] = aff[b][o0+m][k]
    const short8 a = *(const short8*)&affb[((size_t)b * C + o0 + n) * C8 + quad * 8];

    float4v acc[16];
    #pragma unroll
    for (int nt = 0; nt < 16; ++nt) acc[nt] = (float4v){0.f, 0.f, 0.f, 0.f};

    #pragma unroll 4
    for (int nt = 0; nt < 16; ++nt) {
        const size_t pxb = ((size_t)b * HW + px0 + nt * 16 + n) * C8 + quad * 8;
        // B-frag: B[k=quad*8+j][n(px)=lane&15]; wave reads 1KB contiguous
        short8 y0 = *(const short8*)&Yp[((size_t)0 * B * HW) * C8 + pxb];
        short8 y1 = *(const short8*)&Yp[((size_t)1 * B * HW) * C8 + pxb];
        short8 y2 = *(const short8*)&Yp[((size_t)2 * B * HW) * C8 + pxb];
        short8 y3 = *(const short8*)&Yp[((size_t)3 * B * HW) * C8 + pxb];
        acc[nt] = __builtin_amdgcn_mfma_f32_16x16x32_bf16(a, y0, acc[nt], 0, 0, 0);
        acc[nt] = __builtin_amdgcn_mfma_f32_16x16x32_bf16(a, y1, acc[nt], 0, 0, 0);
        acc[nt] = __builtin_amdgcn_mfma_f32_16x16x32_bf16(a, y2, acc[nt], 0, 0, 0);
        acc[nt] = __builtin_amdgcn_mfma_f32_16x16x32_bf16(a, y3, acc[nt], 0, 0, 0);
    }

    // D: col=lane&15 -> px, row=quad*4+reg -> o
    #pragma unroll
    for (int nt = 0; nt < 16; ++nt) {
        #pragma unroll
        for (int reg = 0; reg < 4; ++reg) {
            out[((size_t)b * C + o0 + quad * 4 + reg) * HW + px0 + nt * 16 + n] = acc[nt][reg];
        }
    }
}

extern "C" void kernel_launch(void* const* d_in, const int* in_sizes, int n_in,
                              void* d_out, int out_size, void* d_ws, size_t ws_size,
                              hipStream_t stream) {
    const float* x1  = (const float*)d_in[0];
    const float* x   = (const float*)d_in[1];
    const float* wq  = (const float*)d_in[2];
    const float* bq  = (const float*)d_in[3];
    const float* wk  = (const float*)d_in[4];
    const float* bk  = (const float*)d_in[5];
    const float* con = (const float*)d_in[6];
    float* out = (float*)d_out;

    float* ws = (float*)d_ws;
    // persistent across whole launch:
    unsigned short* affb = (unsigned short*)ws;             // 65536 bf16 = 32768 f
    unsigned short* aswz = (unsigned short*)(ws + 65536);   // 73728 bf16 = 36864 f
    // pool/proj scratch (dead after aff_kernel):
    float* px1 = ws + 102400;                               // 573440 f
    float* px  = ws + 675840;                               // 573440 f
    float* PQ  = ws + 1249280;                              // 573440 f
    float* PK  = ws + 1822720;                              // 71680 f  -> end 1894400
    // xbf ALIASES the pool/proj scratch (x2bf launches after aff_kernel):
    unsigned short* xbf = (unsigned short*)(ws + 102400);   // 8*9216*256 bf16 = 9437184 f
    unsigned short* Yp  = (unsigned short*)(ws + 9539584);  // 4*8*9216*32 bf16 = 4718592 f
    // total: 14258176 floats = 57.0 MB

    aswz_kernel<<<288, 256, 0, stream>>>(con, aswz);
    pool_kernel<<<4096, 256, 0, stream>>>(x1, x, px1, px);
    proj_kernel<<<B * 72, 320, 0, stream>>>(px1, px, wq, bq, wk, bk, PQ, PK);
    aff_kernel<<<B * 32, 256, 0, stream>>>(PQ, PK, affb);
    x2bf_kernel<<<4608, 256, 0, stream>>>(x1, xbf);         // after aff: aliasing safe
    yconv_mfma<<<768, 256, 0, stream>>>(xbf, aswz, Yp);
    mix_kernel<<<1152, 256, 0, stream>>>(Yp, affb, out);
}

// Round 4
// 282.915 us; speedup vs baseline: 1.2644x; 1.2644x over previous
//
#include <hip/hip_runtime.h>
#include <hip/hip_bf16.h>

// Problem: B=8, C=256, H=W=96, c8=32, pool sizes {1,3,5,7,14} -> 280 positions.
// Restructured: out[b,o] = sum_k aff[b,o,k] * conv3x3(x_1[b], con[k])
//               psp(wq@x+bq) = wq@psp(x)+bq  (pool rows sum to 1)
// yconv as implicit-GEMM bf16 MFMA; mix as MFMA GEMM over K=32 with kc summed
// in the accumulator (Yp layout [kc][b][px][k], aff stored bf16 [b][o][k]).

#define B 8
#define C 256
#define C8 32
#define H 96
#define W 96
#define HW 9216
#define NPOS 280
#define NWBIN 30
#define PLS 100   // plane LDS stride (floats)
#define RPS 108   // rowp stride (floats), aliases plane after phase 1
#define OTS 68    // mix epilogue LDS stride (floats): 2-way banks on write+read

typedef __attribute__((ext_vector_type(8))) short short8;
typedef __attribute__((ext_vector_type(4))) float float4v;
typedef __attribute__((ext_vector_type(4))) unsigned short ushort4v;

static __device__ __forceinline__ unsigned short f2bf(float f) {
    unsigned u = __float_as_uint(f);
    unsigned r = (u + 0x7FFF + ((u >> 16) & 1)) >> 16;   // RNE
    return (unsigned short)r;
}

// Accumulate one half-row (48 elems starting at compile-time W0) into the 30
// w-bins. All bin edges are compile-time constants -> straight-line v_add_f32.
template<int W0>
static __device__ __forceinline__ void accum_half_row(const float* __restrict__ pl,
                                                      float acc[NWBIN]) {
    const int SC[5]   = {1, 3, 5, 7, 14};
    const int WOFF[5] = {0, 1, 4, 9, 16};
    #pragma unroll
    for (int k = 0; k < NWBIN; ++k) acc[k] = 0.f;
    #pragma unroll
    for (int c = 0; c < 12; ++c) {
        float4 v = *(const float4*)&pl[W0 + 4 * c];
        float vv[4] = {v.x, v.y, v.z, v.w};
        #pragma unroll
        for (int q = 0; q < 4; ++q) {
            const int w = W0 + 4 * c + q;
            #pragma unroll
            for (int si = 0; si < 5; ++si) {
                #pragma unroll
                for (int j = 0; j < SC[si]; ++j) {
                    const int st = (j * 96) / SC[si];
                    const int en = (96 * (j + 1) + SC[si] - 1) / SC[si];
                    if (w >= st && w < en) acc[WOFF[si] + j] += vv[q];
                }
            }
        }
    }
}

// ---------------- pooling: [B,C,96,96] -> [B,C,280] for both x_1 and x ----
__global__ __launch_bounds__(256) void pool_kernel(const float* __restrict__ x1,
                                                   const float* __restrict__ x,
                                                   float* __restrict__ px1,
                                                   float* __restrict__ px) {
    __shared__ __align__(16) float plane[96 * PLS];   // 38400 B
    float* rowp = plane;                              // alias after phase 1
    const int bi = blockIdx.x;           // 0..4095
    const int which = bi >> 11;          // 0: x_1, 1: x
    const int bc = bi & 2047;
    const float* __restrict__ src = (which ? x : x1) + (size_t)bc * HW;
    float* __restrict__ dst = (which ? px : px1) + (size_t)bc * NPOS;
    const int tid = threadIdx.x;

    const int SC[5]   = {1, 3, 5, 7, 14};
    const int WOFF[5] = {0, 1, 4, 9, 16};
    const int POFF[5] = {0, 1, 10, 35, 84};

    // stage plane: coalesced float4 global -> b128 LDS, stride-100 rows
    const float4* __restrict__ src4 = (const float4*)src;
    #pragma unroll
    for (int it = 0; it < 9; ++it) {
        int idx = tid + it * 256;        // 0..2303
        float4 v = src4[idx];
        int h = idx / 24;
        int w4 = idx - h * 24;
        *(float4*)&plane[h * PLS + w4 * 4] = v;
    }
    __syncthreads();

    // phase 1: w-bin accumulation into registers, one thread per half-row
    float acc[NWBIN];
    if (tid < 96) {                              // rows, w in [0,48)
        accum_half_row<0>(&plane[tid * PLS], acc);
    } else if (tid >= 128 && tid < 224) {        // rows, w in [48,96)
        accum_half_row<48>(&plane[(tid - 128) * PLS], acc);
    }
    __syncthreads();          // ALL plane reads complete; safe to alias

    if (tid >= 128 && tid < 224) {
        const int h1 = tid - 128;
        #pragma unroll
        for (int si = 0; si < 5; ++si) {
            #pragma unroll
            for (int j = 0; j < SC[si]; ++j)
                rowp[(WOFF[si] + j) * RPS + h1] = acc[WOFF[si] + j];
        }
    }
    __syncthreads();
    // combine halves + scale by 1/(w-bin width)
    if (tid < 96) {
        #pragma unroll
        for (int si = 0; si < 5; ++si) {
            #pragma unroll
            for (int j = 0; j < SC[si]; ++j) {
                const int st = (j * 96) / SC[si];
                const int en = (96 * (j + 1) + SC[si] - 1) / SC[si];
                const float inv = 1.0f / (float)(en - st);
                const int bin = WOFF[si] + j;
                rowp[bin * RPS + tid] = (acc[bin] + rowp[bin * RPS + tid]) * inv;
            }
        }
    }
    __syncthreads();

    // phase C: in-place prefix sum over h per w-bin (30 threads, b128)
    if (tid < NWBIN) {
        float run = 0.f;
        #pragma unroll
        for (int c = 0; c < 24; ++c) {
            float4 v = *(const float4*)&rowp[tid * RPS + 4 * c];
            v.x += run; v.y += v.x; v.z += v.y; v.w += v.z;
            run = v.w;
            *(float4*)&rowp[tid * RPS + 4 * c] = v;
        }
    }
    __syncthreads();

    // phase D: 280 outputs, each = prefix difference * 1/(h-bin width)
    for (int p = tid; p < NPOS; p += 256) {
        int si;
        if (p < 1) si = 0; else if (p < 10) si = 1; else if (p < 35) si = 2;
        else if (p < 84) si = 3; else si = 4;
        int s = SC[si];
        int loc = p - POFF[si];
        int i = loc / s;
        int j = loc - i * s;
        int st = (i * 96) / s;
        int en = (96 * (i + 1) + s - 1) / s;
        int binrow = WOFF[si] + j;
        float hi = rowp[binrow * RPS + (en - 1)];
        float lo = (st > 0) ? rowp[binrow * RPS + (st - 1)] : 0.f;
        dst[p] = (hi - lo) * (1.0f / (float)(en - st));
    }
}

// ---------------- proj: PQ = wq@px1+bq [B,256,280]; PK = wk@px+bk [B,32,280]
__global__ __launch_bounds__(320) void proj_kernel(const float* __restrict__ px1,
                                                   const float* __restrict__ px,
                                                   const float* __restrict__ wq,
                                                   const float* __restrict__ bq,
                                                   const float* __restrict__ wk,
                                                   const float* __restrict__ bk,
                                                   float* __restrict__ PQ,
                                                   float* __restrict__ PK) {
    const int bi = blockIdx.x;   // B * 72
    const int b = bi / 72;
    const int r = bi % 72;
    const int tid = threadIdx.x;
    const float* src;
    const float* wm;
    const float* bias;
    float* dst;
    int o0;
    if (r < 64) {
        o0 = r * 4;
        src = px1 + (size_t)b * C * NPOS;
        wm = wq; bias = bq;
        dst = PQ + ((size_t)b * C + o0) * NPOS;
    } else {
        o0 = (r - 64) * 4;
        src = px + (size_t)b * C * NPOS;
        wm = wk; bias = bk;
        dst = PK + ((size_t)b * C8 + o0) * NPOS;
    }
    if (tid >= NPOS) return;
    float a0 = 0.f, a1 = 0.f, a2 = 0.f, a3 = 0.f;
    for (int c = 0; c < C; ++c) {
        float xv = src[c * NPOS + tid];
        a0 += wm[(o0 + 0) * C + c] * xv;
        a1 += wm[(o0 + 1) * C + c] * xv;
        a2 += wm[(o0 + 2) * C + c] * xv;
        a3 += wm[(o0 + 3) * C + c] * xv;
    }
    dst[0 * NPOS + tid] = a0 + bias[o0 + 0];
    dst[1 * NPOS + tid] = a1 + bias[o0 + 1];
    dst[2 * NPOS + tid] = a2 + bias[o0 + 2];
    dst[3 * NPOS + tid] = a3 + bias[o0 + 3];
}

// ---------------- aff[b,o,k] = sigmoid(PQ[b,o,:] . PK[b,k,:]) -> bf16 ------
__global__ __launch_bounds__(256) void aff_kernel(const float* __restrict__ PQ,
                                                  const float* __restrict__ PK,
                                                  unsigned short* __restrict__ affb) {
    __shared__ float pk[NPOS];
    const int b = blockIdx.x >> 5;
    const int k = blockIdx.x & 31;
    const int tid = threadIdx.x;
    const float* __restrict__ pkr = PK + ((size_t)b * C8 + k) * NPOS;
    if (tid < 256) pk[tid] = pkr[tid];
    if (tid < NPOS - 256) pk[tid + 256] = pkr[tid + 256];
    __syncthreads();
    const float4* __restrict__ q4 = (const float4*)(PQ + ((size_t)b * C + tid) * NPOS);
    const float4* __restrict__ p4 = (const float4*)pk;
    float acc = 0.f;
    #pragma unroll 10
    for (int i = 0; i < NPOS / 4; ++i) {
        float4 a = q4[i];
        float4 c = p4[i];
        acc += a.x * c.x + a.y * c.y + a.z * c.z + a.w * c.w;
    }
    float s = 1.0f / (1.0f + __expf(-acc));
    affb[((size_t)b * C + tid) * C8 + k] = f2bf(s);
}

// ---------------- prep: con[k,c,3,3] -> Aswz in MFMA A-fragment order ------
__global__ __launch_bounds__(256) void aswz_kernel(const float* __restrict__ con,
                                                   unsigned short* __restrict__ aswz) {
    int idx = blockIdx.x * 256 + threadIdx.x;   // 72*2*64*8 = 73728
    if (idx >= 73728) return;
    int j = idx & 7;
    int lane = (idx >> 3) & 63;
    int mt = (idx >> 9) & 1;
    int s = idx >> 10;          // 0..71
    int pos = s >> 3;
    int cg = s & 7;
    int m = lane & 15, quad = lane >> 4;
    int ko = mt * 16 + m;
    int c = cg * 32 + quad * 8 + j;
    int dy = pos / 3, dx = pos - dy * 3;
    float v = con[((ko * C + c) * 3 + dy) * 3 + dx];
    aswz[idx] = f2bf(v);
}

// ---------------- transpose x1[b,c,pix] f32 -> xbf[b,pix,c] bf16 -----------
__global__ __launch_bounds__(256) void x2bf_kernel(const float* __restrict__ x1,
                                                   unsigned short* __restrict__ xbf) {
    __shared__ unsigned short tl[64 * 65];
    const int bi = blockIdx.x;
    const int b = bi / 576;
    const int rem = bi % 576;
    const int pt = rem >> 2;
    const int ct = rem & 3;
    const int p0 = pt * 64, c0 = ct * 64;
    const int wid = threadIdx.x >> 6;
    const int lane = threadIdx.x & 63;

    #pragma unroll
    for (int it = 0; it < 16; ++it) {
        int r = it * 4 + wid;   // channel within tile
        tl[r * 65 + lane] = f2bf(x1[((size_t)(b * C + c0 + r)) * HW + p0 + lane]);
    }
    __syncthreads();
    #pragma unroll
    for (int it = 0; it < 16; ++it) {
        int pr = it * 4 + wid;  // pixel within tile
        xbf[((size_t)b * HW + p0 + pr) * 256 + c0 + lane] = tl[lane * 65 + pr];
    }
}

// ---------------- Y = W @ im2col(x1) via MFMA, K split over 4 blocks -------
// Output layout: Yp[kc][b][px][k] bf16 (k contiguous) for MFMA-ready mix.
__global__ __launch_bounds__(256) void yconv_mfma(const unsigned short* __restrict__ xbf,
                                                  const unsigned short* __restrict__ aswz,
                                                  unsigned short* __restrict__ Yp) {
    __shared__ unsigned short xsl[10 * 50 * 40];   // [row][col][ch pad 40] = 40000 B
    const int bi = blockIdx.x;
    const int kc = bi & 3;
    const int rest = bi >> 2;          // 0..191
    const int tilex = rest & 1;
    const int tiley = (rest >> 1) % 12;
    const int b = rest / 24;
    const int tid = threadIdx.x;
    const int wid = tid >> 6;
    const int lane = tid & 63;
    const int n = lane & 15, quad = lane >> 4;

    float4v acc[2][6];
    #pragma unroll
    for (int mt = 0; mt < 2; ++mt)
        #pragma unroll
        for (int t = 0; t < 6; ++t)
            acc[mt][t] = (float4v){0.f, 0.f, 0.f, 0.f};

    int baseb[6];
    #pragma unroll
    for (int t = 0; t < 6; ++t) {
        int tt = wid * 6 + t;
        int rt = tt / 3;
        int xb = (tt % 3) * 16;
        baseb[t] = (rt * 50 + xb + n) * 40 + quad * 8;
    }

    for (int ci = 0; ci < 2; ++ci) {
        const int cg = kc * 2 + ci;
        __syncthreads();
        // stage X slab: 10 rows x 50 cols x 32 ch bf16, pure uint4 copies
        for (int task = tid; task < 2000; task += 256) {
            int pix = task >> 2;       // 0..499
            int cq = task & 3;
            int r = pix / 50;
            int col = pix - r * 50;
            int gy = tiley * 8 + r - 1;
            int gx = tilex * 48 + col - 1;
            uint4 v = make_uint4(0u, 0u, 0u, 0u);
            if ((unsigned)gy < 96u && (unsigned)gx < 96u)
                v = *(const uint4*)&xbf[((size_t)b * HW + gy * 96 + gx) * 256 + cg * 32 + cq * 8];
            *(uint4*)&xsl[(r * 50 + col) * 40 + cq * 8] = v;
        }
        // A-fragments straight from global (L2-hot, 18 x 16B per lane)
        short8 af[9][2];
        #pragma unroll
        for (int pos = 0; pos < 9; ++pos)
            #pragma unroll
            for (int mt = 0; mt < 2; ++mt)
                af[pos][mt] = *(const short8*)&aswz[((((pos * 8 + cg) * 2) + mt) * 64 + lane) * 8];
        __syncthreads();

        #pragma unroll
        for (int pos = 0; pos < 9; ++pos) {
            const int dy = pos / 3, dx = pos - (pos / 3) * 3;
            const int d = (dy * 50 + dx) * 40;
            #pragma unroll
            for (int t = 0; t < 6; ++t) {
                short8 bf = *(const short8*)&xsl[baseb[t] + d];
                acc[0][t] = __builtin_amdgcn_mfma_f32_16x16x32_bf16(af[pos][0], bf, acc[0][t], 0, 0, 0);
                acc[1][t] = __builtin_amdgcn_mfma_f32_16x16x32_bf16(af[pos][1], bf, acc[1][t], 0, 0, 0);
            }
        }
    }

    // store partial: D col=lane&15 -> pixel n, row=quad*4+reg -> k_out.
    // Layout [kc][b][px][k]: 4 consecutive regs = 4 consecutive k -> 8B store.
    #pragma unroll
    for (int mt = 0; mt < 2; ++mt) {
        #pragma unroll
        for (int t = 0; t < 6; ++t) {
            int tt = wid * 6 + t;
            int rt = tt / 3;
            int xb = (tt % 3) * 16;
            int gy = tiley * 8 + rt;
            int gx = tilex * 48 + xb + n;
            ushort4v v;
            #pragma unroll
            for (int reg = 0; reg < 4; ++reg) v[reg] = f2bf(acc[mt][t][reg]);
            *(ushort4v*)&Yp[((((size_t)kc * B + b) * HW + gy * 96 + gx)) * C8 + mt * 16 + quad * 4] = v;
        }
    }
}

// ---------------- mix: out[b,o,px] = sum_k aff[b,o,k] * sum_kc Yp ----------
// v3: block = 64-px strip x ALL 256 o (Yp read exactly once, aff L2-hot),
// fully-unrolled register accumulators (16 tiles), LDS-transpose epilogue so
// every global store is a 256B contiguous wave write.
// grid = 8 b * 144 strips = 1152 blocks, 4 waves.
__global__ __launch_bounds__(256) void mix_kernel(const unsigned short* __restrict__ Yp,
                                                  const unsigned short* __restrict__ affb,
                                                  float* __restrict__ out) {
    __shared__ float ot[128 * OTS];   // 34816 B
    const int bi = blockIdx.x;   // 1152
    const int b = bi / 144;
    const int pg = bi % 144;
    const int wid = threadIdx.x >> 6;
    const int lane = threadIdx.x & 63;
    const int n = lane & 15, quad = lane >> 4;
    const int px0 = pg * 64 + wid * 16;   // this wave's 16-px column tile

    // B-frags, one per kc: B[k=quad*8+j][n(px)] ; wave reads 1KB contiguous
    short8 y0 = *(const short8*)&Yp[(((size_t)0 * B + b) * HW + px0 + n) * C8 + quad * 8];
    short8 y1 = *(const short8*)&Yp[(((size_t)1 * B + b) * HW + px0 + n) * C8 + quad * 8];
    short8 y2 = *(const short8*)&Yp[(((size_t)2 * B + b) * HW + px0 + n) * C8 + quad * 8];
    short8 y3 = *(const short8*)&Yp[(((size_t)3 * B + b) * HW + px0 + n) * C8 + quad * 8];

    float4v acc[16];
    #pragma unroll
    for (int mt = 0; mt < 16; ++mt) acc[mt] = (float4v){0.f, 0.f, 0.f, 0.f};

    #pragma unroll
    for (int mt = 0; mt < 16; ++mt) {
        // A-frag: A[m=lane&15][k=quad*8+j] = aff[b][mt*16+m][k]  (L2-hot)
        const short8 a = *(const short8*)&affb[((size_t)b * C + mt * 16 + n) * C8 + quad * 8];
        acc[mt] = __builtin_amdgcn_mfma_f32_16x16x32_bf16(a, y0, acc[mt], 0, 0, 0);
        acc[mt] = __builtin_amdgcn_mfma_f32_16x16x32_bf16(a, y1, acc[mt], 0, 0, 0);
        acc[mt] = __builtin_amdgcn_mfma_f32_16x16x32_bf16(a, y2, acc[mt], 0, 0, 0);
        acc[mt] = __builtin_amdgcn_mfma_f32_16x16x32_bf16(a, y3, acc[mt], 0, 0, 0);
    }

    // epilogue: two halves of 128 o-rows through LDS -> contiguous 256B stores
    #pragma unroll
    for (int half = 0; half < 2; ++half) {
        __syncthreads();
        #pragma unroll
        for (int mt = 0; mt < 8; ++mt) {
            #pragma unroll
            for (int reg = 0; reg < 4; ++reg) {
                // D: col=lane&15 -> px, row=quad*4+reg -> o   (2-way banks, free)
                ot[(mt * 16 + quad * 4 + reg) * OTS + wid * 16 + n] = acc[half * 8 + mt][reg];
            }
        }
        __syncthreads();
        #pragma unroll
        for (int i = 0; i < 32; ++i) {
            int o = wid * 32 + i;          // local o within half
            out[((size_t)b * C + half * 128 + o) * HW + pg * 64 + lane] = ot[o * OTS + lane];
        }
    }
}

extern "C" void kernel_launch(void* const* d_in, const int* in_sizes, int n_in,
                              void* d_out, int out_size, void* d_ws, size_t ws_size,
                              hipStream_t stream) {
    const float* x1  = (const float*)d_in[0];
    const float* x   = (const float*)d_in[1];
    const float* wq  = (const float*)d_in[2];
    const float* bq  = (const float*)d_in[3];
    const float* wk  = (const float*)d_in[4];
    const float* bk  = (const float*)d_in[5];
    const float* con = (const float*)d_in[6];
    float* out = (float*)d_out;

    float* ws = (float*)d_ws;
    // persistent across whole launch:
    unsigned short* affb = (unsigned short*)ws;             // 65536 bf16 = 32768 f
    unsigned short* aswz = (unsigned short*)(ws + 65536);   // 73728 bf16 = 36864 f
    // pool/proj scratch (dead after aff_kernel):
    float* px1 = ws + 102400;                               // 573440 f
    float* px  = ws + 675840;                               // 573440 f
    float* PQ  = ws + 1249280;                              // 573440 f
    float* PK  = ws + 1822720;                              // 71680 f  -> end 1894400
    // xbf ALIASES the pool/proj scratch (x2bf launches after aff_kernel):
    unsigned short* xbf = (unsigned short*)(ws + 102400);   // 8*9216*256 bf16 = 9437184 f
    unsigned short* Yp  = (unsigned short*)(ws + 9539584);  // 4*8*9216*32 bf16 = 4718592 f
    // total: 14258176 floats = 57.0 MB

    aswz_kernel<<<288, 256, 0, stream>>>(con, aswz);
    pool_kernel<<<4096, 256, 0, stream>>>(x1, x, px1, px);
    proj_kernel<<<B * 72, 320, 0, stream>>>(px1, px, wq, bq, wk, bk, PQ, PK);
    aff_kernel<<<B * 32, 256, 0, stream>>>(PQ, PK, affb);
    x2bf_kernel<<<4608, 256, 0, stream>>>(x1, xbf);         // after aff: aliasing safe
    yconv_mfma<<<768, 256, 0, stream>>>(xbf, aswz, Yp);
    mix_kernel<<<1152, 256, 0, stream>>>(Yp, affb, out);
}